// Round 5
// baseline (210.425 us; speedup 1.0000x reference)
//
#include <hip/hip_runtime.h>

// SRNet via MFMA (v_mfma_f32_32x32x16_f16), D = W * X^T, 2 pixel-groups per
// wave interleaved for ILP, 2 waves/SIMD (grid 512, launch_bounds(256,2)).
// Biases are pre-loaded into the MFMA C accumulator in f32 via broadcast
// ds_read_b128 in exact D-layout (rows 32mt+8q+4lo+{0..3} contiguous in b[]),
// so the epilogue is just cvt_pkrtz -> pk_max -> 8x permlane32_swap.

typedef _Float16 f16x8  __attribute__((ext_vector_type(8)));
typedef _Float16 half2v __attribute__((ext_vector_type(2)));
typedef float    f32x16 __attribute__((ext_vector_type(16)));
typedef unsigned int u32;

union FragU { f16x8 v; u32 w[4]; };

__device__ __forceinline__ u32 pkrne(float a, float b) {
    half2v h; h.x = (_Float16)a; h.y = (_Float16)b;
    return __builtin_bit_cast(u32, h);
}
__device__ __forceinline__ u32 pkrtz(float a, float b) {
    return __builtin_bit_cast(u32, __builtin_amdgcn_cvt_pkrtz(a, b));
}
__device__ __forceinline__ u32 pk_relu(u32 a) {
    half2v z = {};
    half2v r = __builtin_elementwise_max(__builtin_bit_cast(half2v, a), z);
    return __builtin_bit_cast(u32, r);
}

__device__ __forceinline__ f32x16 mfma16(const FragU& a, const FragU& b, f32x16 c) {
    return __builtin_amdgcn_mfma_f32_32x32x16_f16(a.v, b.v, c, 0, 0, 0);
}

// permlane32_swap: ret0[l] = l<32 ? a[l] : b[l-32];  ret1[l] = l<32 ? a[l+32] : b[l]
__device__ __forceinline__ void pl32(u32& x, u32& y) {
    auto r = __builtin_amdgcn_permlane32_swap((int)x, (int)y, false, false);
    x = (u32)r[0]; y = (u32)r[1];
}

__device__ __forceinline__ void calc_coords(int g, int m, int& b, int& hp, int& wp) {
    unsigned P = (unsigned)(g * 32 + m);
    unsigned bb = P / 64516u;            // 254*254
    unsigned rem = P - bb * 64516u;
    unsigned h = rem / 254u;
    b = (int)bb; hp = (int)h; wp = (int)(rem - h * 254u);
}

// One pixel-group's per-iteration prep: coords -> patch loads + output offset.
__device__ __forceinline__ void prep_group(const float* __restrict__ x_in,
                                           int g, int m, int lo,
                                           float p[9], u32& ooff) {
    constexpr int OW = 1016;
    int b, hp, wp;
    calc_coords(g, m, b, hp, wp);
    const float* base = x_in + ((size_t)b << 16) + hp * 256 + wp;
#pragma unroll
    for (int i = 0; i < 3; ++i)
#pragma unroll
        for (int j = 0; j < 3; ++j)
            p[i * 3 + j] = base[i * 256 + j];
    ooff = (u32)b * (OW * OW) + (u32)(4 * hp + lo) * OW + 4 * wp;
}

// Init both groups' accumulators with bias in D-layout (f32, LDS broadcast).
__device__ __forceinline__ void init_bias(f32x16& a0, f32x16& a1,
                                          f32x16& b0, f32x16& b1v,
                                          const float* __restrict__ bb, int lo) {
#pragma unroll
    for (int mt = 0; mt < 2; ++mt) {
#pragma unroll
        for (int q = 0; q < 4; ++q) {
            const float4 t = *(const float4*)(bb + 32 * mt + 8 * q + 4 * lo);
            f32x16& A = mt ? a1 : a0;
            f32x16& B = mt ? b1v : b0;
            A[4 * q + 0] = t.x; A[4 * q + 1] = t.y;
            A[4 * q + 2] = t.z; A[4 * q + 3] = t.w;
            B[4 * q + 0] = t.x; B[4 * q + 1] = t.y;
            B[4 * q + 2] = t.z; B[4 * q + 3] = t.w;
        }
    }
}

// acc(2 tiles, D-layout, bias pre-added) -> relu -> f16 -> permlane -> B frags
__device__ __forceinline__ void epilogue(const f32x16& A0, const f32x16& A1,
                                         FragU (&B)[4]) {
    u32 ww[2][4][2];
#pragma unroll
    for (int mt = 0; mt < 2; ++mt) {
        const f32x16& A = mt ? A1 : A0;
#pragma unroll
        for (int q = 0; q < 4; ++q) {
            ww[mt][q][0] = pk_relu(pkrtz(A[4 * q + 0], A[4 * q + 1]));
            ww[mt][q][1] = pk_relu(pkrtz(A[4 * q + 2], A[4 * q + 3]));
        }
    }
#pragma unroll
    for (int ks = 0; ks < 4; ++ks) {
#pragma unroll
        for (int p = 0; p < 2; ++p) {
            u32 a = ww[ks >> 1][2 * (ks & 1) + 0][p];
            u32 b = ww[ks >> 1][2 * (ks & 1) + 1][p];
            pl32(a, b);
            B[ks].w[p]     = a;
            B[ks].w[p + 2] = b;
        }
    }
}

__device__ __forceinline__ void pack_B1(const float p[9], int lo, FragU& B1) {
    if (lo == 0) {
        B1.w[0] = pkrtz(p[0], p[1]);
        B1.w[1] = pkrtz(p[2], p[3]);
        B1.w[2] = pkrtz(p[4], p[5]);
        B1.w[3] = pkrtz(p[6], p[7]);
    } else {
        B1.w[0] = pkrtz(p[8], 0.0f);
        B1.w[1] = 0; B1.w[2] = 0; B1.w[3] = 0;
    }
}

__global__ __launch_bounds__(256, 2) void srnet_mfma(
    const float* __restrict__ x_in,
    const float* __restrict__ sampler_w,
    const float* __restrict__ w1, const float* __restrict__ b1,
    const float* __restrict__ w2, const float* __restrict__ b2,
    const float* __restrict__ w3, const float* __restrict__ b3,
    const float* __restrict__ w4, const float* __restrict__ b4,
    const float* __restrict__ w5, const float* __restrict__ b5,
    const float* __restrict__ w6, const float* __restrict__ b6,
    float* __restrict__ out)
{
    constexpr int NPAIR = 16129;     // (16*254*254/32) / 2
    constexpr int OW    = 1016;

    const int lane = threadIdx.x & 63;
    const int m    = lane & 31;
    const int lo   = lane >> 5;

    // ---- LDS: f32 biases b1..b5 at [0:320), b6 at [320:336) ----
    __shared__ __align__(16) float bias_f32[336];
    for (int i = threadIdx.x; i < 336; i += 256) {
        float v;
        if      (i < 64)  v = b1[i];
        else if (i < 128) v = b2[i - 64];
        else if (i < 192) v = b3[i - 128];
        else if (i < 256) v = b4[i - 192];
        else if (i < 320) v = b5[i - 256];
        else              v = b6[i - 320];
        bias_f32[i] = v;
    }
    __syncthreads();

    // ---- uniform softmax of sampler (4 x 9) ----
    float ws[4][9];
#pragma unroll
    for (int c = 0; c < 4; ++c) {
        float mx = sampler_w[c * 9];
#pragma unroll
        for (int k = 1; k < 9; ++k) mx = fmaxf(mx, sampler_w[c * 9 + k]);
        float e[9]; float sum = 0.f;
#pragma unroll
        for (int k = 0; k < 9; ++k) { e[k] = __expf(sampler_w[c * 9 + k] - mx); sum += e[k]; }
        float inv = 1.f / sum;
#pragma unroll
        for (int k = 0; k < 9; ++k) ws[c][k] = e[k] * inv;
    }

    // ---- layer-1 effective weights (sampler folded in); bias via C-init ----
    FragU w1f[2];
#pragma unroll
    for (int mt = 0; mt < 2; ++mt) {
        const int row = 32 * mt + m;
        const float4 wr = *(const float4*)(w1 + row * 4);
        float we[9];
#pragma unroll
        for (int k = 0; k < 9; ++k)
            we[k] = wr.x * ws[0][k] + wr.y * ws[1][k] + wr.z * ws[2][k] + wr.w * ws[3][k];
        if (lo == 0) {
            w1f[mt].w[0] = pkrne(we[0], we[1]);
            w1f[mt].w[1] = pkrne(we[2], we[3]);
            w1f[mt].w[2] = pkrne(we[4], we[5]);
            w1f[mt].w[3] = pkrne(we[6], we[7]);
        } else {
            w1f[mt].w[0] = pkrne(we[8], 0.f);
            w1f[mt].w[1] = 0; w1f[mt].w[2] = 0; w1f[mt].w[3] = 0;
        }
    }

    // ---- hidden-layer weight frags ----
    FragU wf[4][2][4];
    const float* wptr[4] = { w2, w3, w4, w5 };
#pragma unroll
    for (int L = 0; L < 4; ++L)
#pragma unroll
        for (int mt = 0; mt < 2; ++mt)
#pragma unroll
            for (int ks = 0; ks < 4; ++ks) {
                const float* src = wptr[L] + (32 * mt + m) * 64 + 16 * ks + 8 * lo;
                const float4 f0 = *(const float4*)(src);
                const float4 f1 = *(const float4*)(src + 4);
                wf[L][mt][ks].w[0] = pkrne(f0.x, f0.y);
                wf[L][mt][ks].w[1] = pkrne(f0.z, f0.w);
                wf[L][mt][ks].w[2] = pkrne(f1.x, f1.y);
                wf[L][mt][ks].w[3] = pkrne(f1.z, f1.w);
            }

    // ---- output-layer frags (rows 16..31 zero) ----
    FragU w6f[4];
    const bool vrow = (m < 16);
    const int r6 = vrow ? m : 0;
#pragma unroll
    for (int ks = 0; ks < 4; ++ks) {
        const float* src = w6 + r6 * 64 + 16 * ks + 8 * lo;
        const float4 f0 = *(const float4*)(src);
        const float4 f1 = *(const float4*)(src + 4);
        w6f[ks].w[0] = vrow ? pkrne(f0.x, f0.y) : 0;
        w6f[ks].w[1] = vrow ? pkrne(f0.z, f0.w) : 0;
        w6f[ks].w[2] = vrow ? pkrne(f1.x, f1.y) : 0;
        w6f[ks].w[3] = vrow ? pkrne(f1.z, f1.w) : 0;
    }

    // ---- pair loop: wave owns groups (2*pg, 2*pg+1) ----
    const int wid = (int)((blockIdx.x * blockDim.x + threadIdx.x) >> 6);
    const int nw  = (int)((gridDim.x * blockDim.x) >> 6);

    int pg = wid;
    float pa[9], pb[9];
    u32 oa = 0, ob = 0;
    if (pg < NPAIR) {
        prep_group(x_in, 2 * pg + 0, m, lo, pa, oa);
        prep_group(x_in, 2 * pg + 1, m, lo, pb, ob);
    }

    while (pg < NPAIR) {
        const int pgn = pg + nw;

        FragU B1a, B1b;
        pack_B1(pa, lo, B1a);
        pack_B1(pb, lo, B1b);

        // prefetch next pair (patches + out offsets)
        float na[9], nb[9];
        u32 noa = 0, nob = 0;
        if (pgn < NPAIR) {
            prep_group(x_in, 2 * pgn + 0, m, lo, na, noa);
            prep_group(x_in, 2 * pgn + 1, m, lo, nb, nob);
        }

        // ---- layer 1 (bias C-init) ----
        f32x16 aa0, aa1, ab0, ab1;
        init_bias(aa0, aa1, ab0, ab1, bias_f32 + 0, lo);
        aa0 = mfma16(w1f[0], B1a, aa0);
        ab0 = mfma16(w1f[0], B1b, ab0);
        aa1 = mfma16(w1f[1], B1a, aa1);
        ab1 = mfma16(w1f[1], B1b, ab1);

        FragU Ba[4], Bb[4];
        epilogue(aa0, aa1, Ba);
        epilogue(ab0, ab1, Bb);

        // ---- layers 2..5 ----
#pragma unroll
        for (int L = 0; L < 4; ++L) {
            f32x16 ca0, ca1, cb0, cb1;
            init_bias(ca0, ca1, cb0, cb1, bias_f32 + 64 * (L + 1), lo);
#pragma unroll
            for (int ks = 0; ks < 4; ++ks) {
                ca0 = mfma16(wf[L][0][ks], Ba[ks], ca0);
                cb0 = mfma16(wf[L][0][ks], Bb[ks], cb0);
                ca1 = mfma16(wf[L][1][ks], Ba[ks], ca1);
                cb1 = mfma16(wf[L][1][ks], Bb[ks], cb1);
            }
            epilogue(ca0, ca1, Ba);
            epilogue(cb0, cb1, Bb);
        }

        // ---- layer 6 (b6 C-init; rows 16..31 unused) ----
        f32x16 aFa, aFb;
        {
            const float4 t0 = *(const float4*)(bias_f32 + 320 + 4 * lo);
            const float4 t1 = *(const float4*)(bias_f32 + 320 + 8 + 4 * lo);
#pragma unroll
            for (int j = 0; j < 4; ++j) {
                aFa[j]      = ((const float*)&t0)[j];
                aFa[4 + j]  = ((const float*)&t1)[j];
                aFa[8 + j]  = 0.f;
                aFa[12 + j] = 0.f;
            }
            aFb = aFa;
        }
#pragma unroll
        for (int ks = 0; ks < 4; ++ks) {
            aFa = mfma16(w6f[ks], Ba[ks], aFa);
            aFb = mfma16(w6f[ks], Bb[ks], aFb);
        }

        // ---- pixel-shuffle stores (offsets cached from prep) ----
#pragma unroll
        for (int gi = 0; gi < 2; ++gi) {
            const f32x16& aF = gi ? aFb : aFa;
            float* obase = out + (gi ? ob : oa);
            *(float4*)(obase)          = make_float4(aF[0], aF[1], aF[2], aF[3]);
            *(float4*)(obase + 2 * OW) = make_float4(aF[4], aF[5], aF[6], aF[7]);
        }

        pg = pgn;
        oa = noa; ob = nob;
#pragma unroll
        for (int k = 0; k < 9; ++k) { pa[k] = na[k]; pb[k] = nb[k]; }
    }
}

extern "C" void kernel_launch(void* const* d_in, const int* in_sizes, int n_in,
                              void* d_out, int out_size, void* d_ws, size_t ws_size,
                              hipStream_t stream)
{
    const float* x_in      = (const float*)d_in[0];
    const float* sampler_w = (const float*)d_in[1];
    // d_in[2] = sampler_b (reference multiplies it by 0 -> unused)
    const float* w1 = (const float*)d_in[3];
    const float* b1 = (const float*)d_in[4];
    const float* w2 = (const float*)d_in[5];
    const float* b2 = (const float*)d_in[6];
    const float* w3 = (const float*)d_in[7];
    const float* b3 = (const float*)d_in[8];
    const float* w4 = (const float*)d_in[9];
    const float* b4 = (const float*)d_in[10];
    const float* w5 = (const float*)d_in[11];
    const float* b5 = (const float*)d_in[12];
    const float* w6 = (const float*)d_in[13];
    const float* b6 = (const float*)d_in[14];
    float* out = (float*)d_out;

    dim3 grid(512);   // 2 blocks/CU -> 2 waves/SIMD (VGPR<=256)
    dim3 block(256);
    hipLaunchKernelGGL(srnet_mfma, grid, block, 0, stream,
                       x_in, sampler_w, w1, b1, w2, b2, w3, b3,
                       w4, b4, w5, b5, w6, b6, out);
}

// Round 6
// 68.758 us; speedup vs baseline: 3.0604x; 3.0604x over previous
//
#include <hip/hip_runtime.h>

// SRNet via MFMA (v_mfma_f32_32x32x16_f16), D = W * X^T, 2 pixel-groups per
// wave interleaved for ILP. Grid 512 = 2 blocks/CU -> 2 waves/SIMD at ~200
// VGPR (NO launch-bounds register cap: (256,2) forced 128 VGPR + scratch
// spill, FETCH 6.7MB->455MB, 210us. Occupancy comes from grid size instead.)
// Biases ride in the MFMA C accumulator in f32 via broadcast ds_read_b128 in
// exact D-layout; epilogue is cvt_pkrtz -> pk_max -> 8x permlane32_swap.

typedef _Float16 f16x8  __attribute__((ext_vector_type(8)));
typedef _Float16 half2v __attribute__((ext_vector_type(2)));
typedef float    f32x16 __attribute__((ext_vector_type(16)));
typedef unsigned int u32;

union FragU { f16x8 v; u32 w[4]; };

__device__ __forceinline__ u32 pkrne(float a, float b) {
    half2v h; h.x = (_Float16)a; h.y = (_Float16)b;
    return __builtin_bit_cast(u32, h);
}
__device__ __forceinline__ u32 pkrtz(float a, float b) {
    return __builtin_bit_cast(u32, __builtin_amdgcn_cvt_pkrtz(a, b));
}
__device__ __forceinline__ u32 pk_relu(u32 a) {
    half2v z = {};
    half2v r = __builtin_elementwise_max(__builtin_bit_cast(half2v, a), z);
    return __builtin_bit_cast(u32, r);
}

__device__ __forceinline__ f32x16 mfma16(const FragU& a, const FragU& b, f32x16 c) {
    return __builtin_amdgcn_mfma_f32_32x32x16_f16(a.v, b.v, c, 0, 0, 0);
}

// permlane32_swap: ret0[l] = l<32 ? a[l] : b[l-32];  ret1[l] = l<32 ? a[l+32] : b[l]
__device__ __forceinline__ void pl32(u32& x, u32& y) {
    auto r = __builtin_amdgcn_permlane32_swap((int)x, (int)y, false, false);
    x = (u32)r[0]; y = (u32)r[1];
}

__device__ __forceinline__ void calc_coords(int g, int m, int& b, int& hp, int& wp) {
    unsigned P = (unsigned)(g * 32 + m);
    unsigned bb = P / 64516u;            // 254*254
    unsigned rem = P - bb * 64516u;
    unsigned h = rem / 254u;
    b = (int)bb; hp = (int)h; wp = (int)(rem - h * 254u);
}

// One pixel-group's per-iteration prep: coords -> patch loads + output offset.
__device__ __forceinline__ void prep_group(const float* __restrict__ x_in,
                                           int g, int m, int lo,
                                           float p[9], u32& ooff) {
    constexpr int OW = 1016;
    int b, hp, wp;
    calc_coords(g, m, b, hp, wp);
    const float* base = x_in + ((size_t)b << 16) + hp * 256 + wp;
#pragma unroll
    for (int i = 0; i < 3; ++i)
#pragma unroll
        for (int j = 0; j < 3; ++j)
            p[i * 3 + j] = base[i * 256 + j];
    ooff = (u32)b * (OW * OW) + (u32)(4 * hp + lo) * OW + 4 * wp;
}

// Init both groups' accumulators with bias in D-layout (f32, LDS broadcast).
__device__ __forceinline__ void init_bias(f32x16& a0, f32x16& a1,
                                          f32x16& b0, f32x16& b1v,
                                          const float* __restrict__ bb, int lo) {
#pragma unroll
    for (int mt = 0; mt < 2; ++mt) {
#pragma unroll
        for (int q = 0; q < 4; ++q) {
            const float4 t = *(const float4*)(bb + 32 * mt + 8 * q + 4 * lo);
            f32x16& A = mt ? a1 : a0;
            f32x16& B = mt ? b1v : b0;
            A[4 * q + 0] = t.x; A[4 * q + 1] = t.y;
            A[4 * q + 2] = t.z; A[4 * q + 3] = t.w;
            B[4 * q + 0] = t.x; B[4 * q + 1] = t.y;
            B[4 * q + 2] = t.z; B[4 * q + 3] = t.w;
        }
    }
}

// acc(2 tiles, D-layout, bias pre-added) -> relu -> f16 -> permlane -> B frags
__device__ __forceinline__ void epilogue(const f32x16& A0, const f32x16& A1,
                                         FragU (&B)[4]) {
    u32 ww[2][4][2];
#pragma unroll
    for (int mt = 0; mt < 2; ++mt) {
        const f32x16& A = mt ? A1 : A0;
#pragma unroll
        for (int q = 0; q < 4; ++q) {
            ww[mt][q][0] = pk_relu(pkrtz(A[4 * q + 0], A[4 * q + 1]));
            ww[mt][q][1] = pk_relu(pkrtz(A[4 * q + 2], A[4 * q + 3]));
        }
    }
#pragma unroll
    for (int ks = 0; ks < 4; ++ks) {
#pragma unroll
        for (int p = 0; p < 2; ++p) {
            u32 a = ww[ks >> 1][2 * (ks & 1) + 0][p];
            u32 b = ww[ks >> 1][2 * (ks & 1) + 1][p];
            pl32(a, b);
            B[ks].w[p]     = a;
            B[ks].w[p + 2] = b;
        }
    }
}

__device__ __forceinline__ void pack_B1(const float p[9], int lo, FragU& B1) {
    if (lo == 0) {
        B1.w[0] = pkrtz(p[0], p[1]);
        B1.w[1] = pkrtz(p[2], p[3]);
        B1.w[2] = pkrtz(p[4], p[5]);
        B1.w[3] = pkrtz(p[6], p[7]);
    } else {
        B1.w[0] = pkrtz(p[8], 0.0f);
        B1.w[1] = 0; B1.w[2] = 0; B1.w[3] = 0;
    }
}

__global__ __launch_bounds__(256, 1) void srnet_mfma(
    const float* __restrict__ x_in,
    const float* __restrict__ sampler_w,
    const float* __restrict__ w1, const float* __restrict__ b1,
    const float* __restrict__ w2, const float* __restrict__ b2,
    const float* __restrict__ w3, const float* __restrict__ b3,
    const float* __restrict__ w4, const float* __restrict__ b4,
    const float* __restrict__ w5, const float* __restrict__ b5,
    const float* __restrict__ w6, const float* __restrict__ b6,
    float* __restrict__ out)
{
    constexpr int NPAIR = 16129;     // (16*254*254/32) / 2
    constexpr int OW    = 1016;

    const int lane = threadIdx.x & 63;
    const int m    = lane & 31;
    const int lo   = lane >> 5;

    // ---- LDS: f32 biases b1..b5 at [0:320), b6 at [320:336) ----
    __shared__ __align__(16) float bias_f32[336];
    for (int i = threadIdx.x; i < 336; i += 256) {
        float v;
        if      (i < 64)  v = b1[i];
        else if (i < 128) v = b2[i - 64];
        else if (i < 192) v = b3[i - 128];
        else if (i < 256) v = b4[i - 192];
        else if (i < 320) v = b5[i - 256];
        else              v = b6[i - 320];
        bias_f32[i] = v;
    }
    __syncthreads();

    // ---- uniform softmax of sampler (4 x 9) ----
    float ws[4][9];
#pragma unroll
    for (int c = 0; c < 4; ++c) {
        float mx = sampler_w[c * 9];
#pragma unroll
        for (int k = 1; k < 9; ++k) mx = fmaxf(mx, sampler_w[c * 9 + k]);
        float e[9]; float sum = 0.f;
#pragma unroll
        for (int k = 0; k < 9; ++k) { e[k] = __expf(sampler_w[c * 9 + k] - mx); sum += e[k]; }
        float inv = 1.f / sum;
#pragma unroll
        for (int k = 0; k < 9; ++k) ws[c][k] = e[k] * inv;
    }

    // ---- layer-1 effective weights (sampler folded in); bias via C-init ----
    FragU w1f[2];
#pragma unroll
    for (int mt = 0; mt < 2; ++mt) {
        const int row = 32 * mt + m;
        const float4 wr = *(const float4*)(w1 + row * 4);
        float we[9];
#pragma unroll
        for (int k = 0; k < 9; ++k)
            we[k] = wr.x * ws[0][k] + wr.y * ws[1][k] + wr.z * ws[2][k] + wr.w * ws[3][k];
        if (lo == 0) {
            w1f[mt].w[0] = pkrne(we[0], we[1]);
            w1f[mt].w[1] = pkrne(we[2], we[3]);
            w1f[mt].w[2] = pkrne(we[4], we[5]);
            w1f[mt].w[3] = pkrne(we[6], we[7]);
        } else {
            w1f[mt].w[0] = pkrne(we[8], 0.f);
            w1f[mt].w[1] = 0; w1f[mt].w[2] = 0; w1f[mt].w[3] = 0;
        }
    }

    // ---- hidden-layer weight frags ----
    FragU wf[4][2][4];
    const float* wptr[4] = { w2, w3, w4, w5 };
#pragma unroll
    for (int L = 0; L < 4; ++L)
#pragma unroll
        for (int mt = 0; mt < 2; ++mt)
#pragma unroll
            for (int ks = 0; ks < 4; ++ks) {
                const float* src = wptr[L] + (32 * mt + m) * 64 + 16 * ks + 8 * lo;
                const float4 f0 = *(const float4*)(src);
                const float4 f1 = *(const float4*)(src + 4);
                wf[L][mt][ks].w[0] = pkrne(f0.x, f0.y);
                wf[L][mt][ks].w[1] = pkrne(f0.z, f0.w);
                wf[L][mt][ks].w[2] = pkrne(f1.x, f1.y);
                wf[L][mt][ks].w[3] = pkrne(f1.z, f1.w);
            }

    // ---- output-layer frags (rows 16..31 zero) ----
    FragU w6f[4];
    const bool vrow = (m < 16);
    const int r6 = vrow ? m : 0;
#pragma unroll
    for (int ks = 0; ks < 4; ++ks) {
        const float* src = w6 + r6 * 64 + 16 * ks + 8 * lo;
        const float4 f0 = *(const float4*)(src);
        const float4 f1 = *(const float4*)(src + 4);
        w6f[ks].w[0] = vrow ? pkrne(f0.x, f0.y) : 0;
        w6f[ks].w[1] = vrow ? pkrne(f0.z, f0.w) : 0;
        w6f[ks].w[2] = vrow ? pkrne(f1.x, f1.y) : 0;
        w6f[ks].w[3] = vrow ? pkrne(f1.z, f1.w) : 0;
    }

    // ---- pair loop: wave owns groups (2*pg, 2*pg+1) ----
    const int wid = (int)((blockIdx.x * blockDim.x + threadIdx.x) >> 6);
    const int nw  = (int)((gridDim.x * blockDim.x) >> 6);

    int pg = wid;
    float pa[9], pb[9];
    u32 oa = 0, ob = 0;
    if (pg < NPAIR) {
        prep_group(x_in, 2 * pg + 0, m, lo, pa, oa);
        prep_group(x_in, 2 * pg + 1, m, lo, pb, ob);
    }

    while (pg < NPAIR) {
        const int pgn = pg + nw;

        FragU B1a, B1b;
        pack_B1(pa, lo, B1a);
        pack_B1(pb, lo, B1b);

        // prefetch next pair (patches + out offsets)
        float na[9], nb[9];
        u32 noa = 0, nob = 0;
        if (pgn < NPAIR) {
            prep_group(x_in, 2 * pgn + 0, m, lo, na, noa);
            prep_group(x_in, 2 * pgn + 1, m, lo, nb, nob);
        }

        // ---- layer 1 (bias C-init) ----
        f32x16 aa0, aa1, ab0, ab1;
        init_bias(aa0, aa1, ab0, ab1, bias_f32 + 0, lo);
        aa0 = mfma16(w1f[0], B1a, aa0);
        ab0 = mfma16(w1f[0], B1b, ab0);
        aa1 = mfma16(w1f[1], B1a, aa1);
        ab1 = mfma16(w1f[1], B1b, ab1);

        FragU Ba[4], Bb[4];
        epilogue(aa0, aa1, Ba);
        epilogue(ab0, ab1, Bb);

        // ---- layers 2..5 ----
#pragma unroll
        for (int L = 0; L < 4; ++L) {
            f32x16 ca0, ca1, cb0, cb1;
            init_bias(ca0, ca1, cb0, cb1, bias_f32 + 64 * (L + 1), lo);
#pragma unroll
            for (int ks = 0; ks < 4; ++ks) {
                ca0 = mfma16(wf[L][0][ks], Ba[ks], ca0);
                cb0 = mfma16(wf[L][0][ks], Bb[ks], cb0);
                ca1 = mfma16(wf[L][1][ks], Ba[ks], ca1);
                cb1 = mfma16(wf[L][1][ks], Bb[ks], cb1);
            }
            epilogue(ca0, ca1, Ba);
            epilogue(cb0, cb1, Bb);
        }

        // ---- layer 6 (b6 C-init; rows 16..31 unused) ----
        f32x16 aFa, aFb;
        {
            const float4 t0 = *(const float4*)(bias_f32 + 320 + 4 * lo);
            const float4 t1 = *(const float4*)(bias_f32 + 320 + 8 + 4 * lo);
#pragma unroll
            for (int j = 0; j < 4; ++j) {
                aFa[j]      = ((const float*)&t0)[j];
                aFa[4 + j]  = ((const float*)&t1)[j];
                aFa[8 + j]  = 0.f;
                aFa[12 + j] = 0.f;
            }
            aFb = aFa;
        }
#pragma unroll
        for (int ks = 0; ks < 4; ++ks) {
            aFa = mfma16(w6f[ks], Ba[ks], aFa);
            aFb = mfma16(w6f[ks], Bb[ks], aFb);
        }

        // ---- pixel-shuffle stores (offsets cached from prep) ----
#pragma unroll
        for (int gi = 0; gi < 2; ++gi) {
            const f32x16& aF = gi ? aFb : aFa;
            float* obase = out + (gi ? ob : oa);
            *(float4*)(obase)          = make_float4(aF[0], aF[1], aF[2], aF[3]);
            *(float4*)(obase + 2 * OW) = make_float4(aF[4], aF[5], aF[6], aF[7]);
        }

        pg = pgn;
        oa = noa; ob = nob;
#pragma unroll
        for (int k = 0; k < 9; ++k) { pa[k] = na[k]; pb[k] = nb[k]; }
    }
}

extern "C" void kernel_launch(void* const* d_in, const int* in_sizes, int n_in,
                              void* d_out, int out_size, void* d_ws, size_t ws_size,
                              hipStream_t stream)
{
    const float* x_in      = (const float*)d_in[0];
    const float* sampler_w = (const float*)d_in[1];
    // d_in[2] = sampler_b (reference multiplies it by 0 -> unused)
    const float* w1 = (const float*)d_in[3];
    const float* b1 = (const float*)d_in[4];
    const float* w2 = (const float*)d_in[5];
    const float* b2 = (const float*)d_in[6];
    const float* w3 = (const float*)d_in[7];
    const float* b3 = (const float*)d_in[8];
    const float* w4 = (const float*)d_in[9];
    const float* b4 = (const float*)d_in[10];
    const float* w5 = (const float*)d_in[11];
    const float* b5 = (const float*)d_in[12];
    const float* w6 = (const float*)d_in[13];
    const float* b6 = (const float*)d_in[14];
    float* out = (float*)d_out;

    dim3 grid(512);   // 2 blocks/CU -> 2 waves/SIMD at ~200 VGPR (512-reg file)
    dim3 block(256);
    hipLaunchKernelGGL(srnet_mfma, grid, block, 0, stream,
                       x_in, sampler_w, w1, b1, w2, b2, w3, b3,
                       w4, b4, w5, b5, w6, b6, out);
}

// Round 7
// 62.377 us; speedup vs baseline: 3.3734x; 1.1023x over previous
//
#include <hip/hip_runtime.h>

// SRNet via MFMA (v_mfma_f32_32x32x16_f16), D = W * X^T, 2 pixel-groups per
// wave interleaved. Hidden-layer weights (w2..w5) live in LDS fragment-major
// ([L][mt*4+ks][lane] x 16B -> ds_read_b128 at lane*16+const, conflict-free),
// freeing ~128 VGPRs so total regs (VGPR+AGPR) fit 2 waves/SIMD. Round 6
// showed 248 VGPR + ~64 AGPR > 256 kept occupancy at 1 wave/SIMD (10%).
// Biases ride in the MFMA C accumulator via broadcast ds_read_b128 (D-layout).

typedef _Float16 f16x8  __attribute__((ext_vector_type(8)));
typedef _Float16 half2v __attribute__((ext_vector_type(2)));
typedef float    f32x16 __attribute__((ext_vector_type(16)));
typedef unsigned int u32;
typedef u32 u32x4 __attribute__((ext_vector_type(4)));

union FragU { f16x8 v; u32 w[4]; };

__device__ __forceinline__ u32 pkrne(float a, float b) {
    half2v h; h.x = (_Float16)a; h.y = (_Float16)b;
    return __builtin_bit_cast(u32, h);
}
__device__ __forceinline__ u32 pkrtz(float a, float b) {
    return __builtin_bit_cast(u32, __builtin_amdgcn_cvt_pkrtz(a, b));
}
__device__ __forceinline__ u32 pk_relu(u32 a) {
    half2v z = {};
    half2v r = __builtin_elementwise_max(__builtin_bit_cast(half2v, a), z);
    return __builtin_bit_cast(u32, r);
}

__device__ __forceinline__ f32x16 mfma16(const FragU& a, const FragU& b, f32x16 c) {
    return __builtin_amdgcn_mfma_f32_32x32x16_f16(a.v, b.v, c, 0, 0, 0);
}

// permlane32_swap: ret0[l] = l<32 ? a[l] : b[l-32];  ret1[l] = l<32 ? a[l+32] : b[l]
__device__ __forceinline__ void pl32(u32& x, u32& y) {
    auto r = __builtin_amdgcn_permlane32_swap((int)x, (int)y, false, false);
    x = (u32)r[0]; y = (u32)r[1];
}

__device__ __forceinline__ void calc_coords(int g, int m, int& b, int& hp, int& wp) {
    unsigned P = (unsigned)(g * 32 + m);
    unsigned bb = P / 64516u;            // 254*254
    unsigned rem = P - bb * 64516u;
    unsigned h = rem / 254u;
    b = (int)bb; hp = (int)h; wp = (int)(rem - h * 254u);
}

// One pixel-group's per-iteration prep: coords -> patch loads + output offset.
__device__ __forceinline__ void prep_group(const float* __restrict__ x_in,
                                           int g, int m, int lo,
                                           float p[9], u32& ooff) {
    constexpr int OW = 1016;
    int b, hp, wp;
    calc_coords(g, m, b, hp, wp);
    const float* base = x_in + ((size_t)b << 16) + hp * 256 + wp;
#pragma unroll
    for (int i = 0; i < 3; ++i)
#pragma unroll
        for (int j = 0; j < 3; ++j)
            p[i * 3 + j] = base[i * 256 + j];
    ooff = (u32)b * (OW * OW) + (u32)(4 * hp + lo) * OW + 4 * wp;
}

// Init both groups' accumulators with bias in D-layout (f32, LDS broadcast).
__device__ __forceinline__ void init_bias(f32x16& a0, f32x16& a1,
                                          f32x16& b0, f32x16& b1v,
                                          const float* __restrict__ bb, int lo) {
#pragma unroll
    for (int mt = 0; mt < 2; ++mt) {
#pragma unroll
        for (int q = 0; q < 4; ++q) {
            const float4 t = *(const float4*)(bb + 32 * mt + 8 * q + 4 * lo);
            f32x16& A = mt ? a1 : a0;
            f32x16& B = mt ? b1v : b0;
            A[4 * q + 0] = t.x; A[4 * q + 1] = t.y;
            A[4 * q + 2] = t.z; A[4 * q + 3] = t.w;
            B[4 * q + 0] = t.x; B[4 * q + 1] = t.y;
            B[4 * q + 2] = t.z; B[4 * q + 3] = t.w;
        }
    }
}

// acc(2 tiles, D-layout, bias pre-added) -> relu -> f16 -> permlane -> B frags
__device__ __forceinline__ void epilogue(const f32x16& A0, const f32x16& A1,
                                         FragU (&B)[4]) {
    u32 ww[2][4][2];
#pragma unroll
    for (int mt = 0; mt < 2; ++mt) {
        const f32x16& A = mt ? A1 : A0;
#pragma unroll
        for (int q = 0; q < 4; ++q) {
            ww[mt][q][0] = pk_relu(pkrtz(A[4 * q + 0], A[4 * q + 1]));
            ww[mt][q][1] = pk_relu(pkrtz(A[4 * q + 2], A[4 * q + 3]));
        }
    }
#pragma unroll
    for (int ks = 0; ks < 4; ++ks) {
#pragma unroll
        for (int p = 0; p < 2; ++p) {
            u32 a = ww[ks >> 1][2 * (ks & 1) + 0][p];
            u32 b = ww[ks >> 1][2 * (ks & 1) + 1][p];
            pl32(a, b);
            B[ks].w[p]     = a;
            B[ks].w[p + 2] = b;
        }
    }
}

__device__ __forceinline__ void pack_B1(const float p[9], int lo, FragU& B1) {
    if (lo == 0) {
        B1.w[0] = pkrtz(p[0], p[1]);
        B1.w[1] = pkrtz(p[2], p[3]);
        B1.w[2] = pkrtz(p[4], p[5]);
        B1.w[3] = pkrtz(p[6], p[7]);
    } else {
        B1.w[0] = pkrtz(p[8], 0.0f);
        B1.w[1] = 0; B1.w[2] = 0; B1.w[3] = 0;
    }
}

__global__ __launch_bounds__(256, 1) void srnet_mfma(
    const float* __restrict__ x_in,
    const float* __restrict__ sampler_w,
    const float* __restrict__ w1, const float* __restrict__ b1,
    const float* __restrict__ w2, const float* __restrict__ b2,
    const float* __restrict__ w3, const float* __restrict__ b3,
    const float* __restrict__ w4, const float* __restrict__ b4,
    const float* __restrict__ w5, const float* __restrict__ b5,
    const float* __restrict__ w6, const float* __restrict__ b6,
    float* __restrict__ out)
{
    constexpr int NPAIR = 16129;     // (16*254*254/32) / 2
    constexpr int OW    = 1016;

    const int lane = threadIdx.x & 63;
    const int m    = lane & 31;
    const int lo   = lane >> 5;

    // ---- LDS: hidden-layer weight frags [L][mt*4+ks][lane] (32 KB) + biases ----
    __shared__ u32x4 wlds[2048];                 // (4 layers * 8 frags * 64 lanes)
    __shared__ __align__(16) float bias_f32[336];

    const float* wptr[4] = { w2, w3, w4, w5 };
    for (int e = threadIdx.x; e < 2048; e += 256) {
        const int L  = e >> 9;
        const int f  = (e >> 6) & 7;
        const int l  = e & 63;
        const int mt = f >> 2, ks = f & 3;
        const float* src = wptr[L] + (32 * mt + (l & 31)) * 64 + 16 * ks + 8 * (l >> 5);
        const float4 f0 = *(const float4*)(src);
        const float4 f1 = *(const float4*)(src + 4);
        u32x4 v;
        v.x = pkrne(f0.x, f0.y); v.y = pkrne(f0.z, f0.w);
        v.z = pkrne(f1.x, f1.y); v.w = pkrne(f1.z, f1.w);
        wlds[e] = v;
    }
    for (int i = threadIdx.x; i < 336; i += 256) {
        float v;
        if      (i < 64)  v = b1[i];
        else if (i < 128) v = b2[i - 64];
        else if (i < 192) v = b3[i - 128];
        else if (i < 256) v = b4[i - 192];
        else if (i < 320) v = b5[i - 256];
        else              v = b6[i - 320];
        bias_f32[i] = v;
    }
    __syncthreads();

    // ---- uniform softmax of sampler (4 x 9) ----
    float ws[4][9];
#pragma unroll
    for (int c = 0; c < 4; ++c) {
        float mx = sampler_w[c * 9];
#pragma unroll
        for (int k = 1; k < 9; ++k) mx = fmaxf(mx, sampler_w[c * 9 + k]);
        float e[9]; float sum = 0.f;
#pragma unroll
        for (int k = 0; k < 9; ++k) { e[k] = __expf(sampler_w[c * 9 + k] - mx); sum += e[k]; }
        float inv = 1.f / sum;
#pragma unroll
        for (int k = 0; k < 9; ++k) ws[c][k] = e[k] * inv;
    }

    // ---- layer-1 effective weights (sampler folded in); bias via C-init ----
    FragU w1f[2];
#pragma unroll
    for (int mt = 0; mt < 2; ++mt) {
        const int row = 32 * mt + m;
        const float4 wr = *(const float4*)(w1 + row * 4);
        float we[9];
#pragma unroll
        for (int k = 0; k < 9; ++k)
            we[k] = wr.x * ws[0][k] + wr.y * ws[1][k] + wr.z * ws[2][k] + wr.w * ws[3][k];
        if (lo == 0) {
            w1f[mt].w[0] = pkrne(we[0], we[1]);
            w1f[mt].w[1] = pkrne(we[2], we[3]);
            w1f[mt].w[2] = pkrne(we[4], we[5]);
            w1f[mt].w[3] = pkrne(we[6], we[7]);
        } else {
            w1f[mt].w[0] = pkrne(we[8], 0.f);
            w1f[mt].w[1] = 0; w1f[mt].w[2] = 0; w1f[mt].w[3] = 0;
        }
    }

    // ---- output-layer frags (rows 16..31 zero) ----
    FragU w6f[4];
    const bool vrow = (m < 16);
    const int r6 = vrow ? m : 0;
#pragma unroll
    for (int ks = 0; ks < 4; ++ks) {
        const float* src = w6 + r6 * 64 + 16 * ks + 8 * lo;
        const float4 f0 = *(const float4*)(src);
        const float4 f1 = *(const float4*)(src + 4);
        w6f[ks].w[0] = vrow ? pkrne(f0.x, f0.y) : 0;
        w6f[ks].w[1] = vrow ? pkrne(f0.z, f0.w) : 0;
        w6f[ks].w[2] = vrow ? pkrne(f1.x, f1.y) : 0;
        w6f[ks].w[3] = vrow ? pkrne(f1.z, f1.w) : 0;
    }

    // ---- pair loop: wave owns groups (2*pg, 2*pg+1) ----
    const int wid = (int)((blockIdx.x * blockDim.x + threadIdx.x) >> 6);
    const int nw  = (int)((gridDim.x * blockDim.x) >> 6);

    int pg = wid;
    float pa[9], pb[9];
    u32 oa = 0, ob = 0;
    if (pg < NPAIR) {
        prep_group(x_in, 2 * pg + 0, m, lo, pa, oa);
        prep_group(x_in, 2 * pg + 1, m, lo, pb, ob);
    }

    while (pg < NPAIR) {
        const int pgn = pg + nw;

        FragU B1a, B1b;
        pack_B1(pa, lo, B1a);
        pack_B1(pb, lo, B1b);

        // prefetch next pair (patches + out offsets)
        float na[9], nb[9];
        u32 noa = 0, nob = 0;
        if (pgn < NPAIR) {
            prep_group(x_in, 2 * pgn + 0, m, lo, na, noa);
            prep_group(x_in, 2 * pgn + 1, m, lo, nb, nob);
        }

        // ---- layer 1 (bias C-init) ----
        f32x16 aa0, aa1, ab0, ab1;
        init_bias(aa0, aa1, ab0, ab1, bias_f32 + 0, lo);
        aa0 = mfma16(w1f[0], B1a, aa0);
        ab0 = mfma16(w1f[0], B1b, ab0);
        aa1 = mfma16(w1f[1], B1a, aa1);
        ab1 = mfma16(w1f[1], B1b, ab1);

        FragU Ba[4], Bb[4];
        epilogue(aa0, aa1, Ba);
        epilogue(ab0, ab1, Bb);

        // ---- layers 2..5: weight frags from LDS (conflict-free b128) ----
#pragma unroll
        for (int L = 0; L < 4; ++L) {
            FragU Wf[8];
#pragma unroll
            for (int f = 0; f < 8; ++f) {
                u32x4 v = wlds[(L * 8 + f) * 64 + lane];
                Wf[f].w[0] = v.x; Wf[f].w[1] = v.y;
                Wf[f].w[2] = v.z; Wf[f].w[3] = v.w;
            }
            f32x16 ca0, ca1, cb0, cb1;
            init_bias(ca0, ca1, cb0, cb1, bias_f32 + 64 * (L + 1), lo);
#pragma unroll
            for (int ks = 0; ks < 4; ++ks) {
                ca0 = mfma16(Wf[ks],     Ba[ks], ca0);
                cb0 = mfma16(Wf[ks],     Bb[ks], cb0);
                ca1 = mfma16(Wf[4 + ks], Ba[ks], ca1);
                cb1 = mfma16(Wf[4 + ks], Bb[ks], cb1);
            }
            epilogue(ca0, ca1, Ba);
            epilogue(cb0, cb1, Bb);
        }

        // ---- layer 6 (b6 C-init; rows 16..31 unused) ----
        f32x16 aFa, aFb;
        {
            const float4 t0 = *(const float4*)(bias_f32 + 320 + 4 * lo);
            const float4 t1 = *(const float4*)(bias_f32 + 320 + 8 + 4 * lo);
#pragma unroll
            for (int j = 0; j < 4; ++j) {
                aFa[j]      = ((const float*)&t0)[j];
                aFa[4 + j]  = ((const float*)&t1)[j];
                aFa[8 + j]  = 0.f;
                aFa[12 + j] = 0.f;
            }
            aFb = aFa;
        }
#pragma unroll
        for (int ks = 0; ks < 4; ++ks) {
            aFa = mfma16(w6f[ks], Ba[ks], aFa);
            aFb = mfma16(w6f[ks], Bb[ks], aFb);
        }

        // ---- pixel-shuffle stores (offsets cached from prep) ----
#pragma unroll
        for (int gi = 0; gi < 2; ++gi) {
            const f32x16& aF = gi ? aFb : aFa;
            float* obase = out + (gi ? ob : oa);
            *(float4*)(obase)          = make_float4(aF[0], aF[1], aF[2], aF[3]);
            *(float4*)(obase + 2 * OW) = make_float4(aF[4], aF[5], aF[6], aF[7]);
        }

        pg = pgn;
        oa = noa; ob = nob;
#pragma unroll
        for (int k = 0; k < 9; ++k) { pa[k] = na[k]; pb[k] = nb[k]; }
    }
}

extern "C" void kernel_launch(void* const* d_in, const int* in_sizes, int n_in,
                              void* d_out, int out_size, void* d_ws, size_t ws_size,
                              hipStream_t stream)
{
    const float* x_in      = (const float*)d_in[0];
    const float* sampler_w = (const float*)d_in[1];
    // d_in[2] = sampler_b (reference multiplies it by 0 -> unused)
    const float* w1 = (const float*)d_in[3];
    const float* b1 = (const float*)d_in[4];
    const float* w2 = (const float*)d_in[5];
    const float* b2 = (const float*)d_in[6];
    const float* w3 = (const float*)d_in[7];
    const float* b3 = (const float*)d_in[8];
    const float* w4 = (const float*)d_in[9];
    const float* b4 = (const float*)d_in[10];
    const float* w5 = (const float*)d_in[11];
    const float* b5 = (const float*)d_in[12];
    const float* w6 = (const float*)d_in[13];
    const float* b6 = (const float*)d_in[14];
    float* out = (float*)d_out;

    dim3 grid(512);   // 2 blocks/CU; regs now sized for 2 waves/SIMD residency
    dim3 block(256);
    hipLaunchKernelGGL(srnet_mfma, grid, block, 0, stream,
                       x_in, sampler_w, w1, b1, w2, b2, w3, b3,
                       w4, b4, w5, b5, w6, b6, out);
}